// Round 1
// baseline (1281.523 us; speedup 1.0000x reference)
//
#include <hip/hip_runtime.h>
#include <cstdint>
#include <cstddef>

#define TSTEPS 1000
#define NB     256
#define NR     200
#define NI     10
#define ALPHA_F     0.1f
#define NOISE_STD_F 0.01f

// ---------------- JAX threefry2x32-20, key = (0, 42) --------------------
// Partitionable variant (JAX >= 0.5 default): element j uses counter
// (hi=0, lo=j); 32-bit draw = out0 ^ out1.
__device__ __forceinline__ uint32_t rotl32(uint32_t v, uint32_t d) {
  return (v << d) | (v >> (32u - d));
}

__device__ __forceinline__ uint32_t threefry_bits(uint32_t c1) {
  const uint32_t ks0 = 0u;
  const uint32_t ks1 = 42u;
  const uint32_t ks2 = 0x1BD11BDAu ^ ks0 ^ ks1;
  uint32_t x0 = ks0;        // counter hi = 0
  uint32_t x1 = c1 + ks1;   // counter lo = j
#define TFR(r) { x0 += x1; x1 = rotl32(x1, (r)); x1 ^= x0; }
  TFR(13) TFR(15) TFR(26) TFR(6)   x0 += ks1; x1 += ks2 + 1u;
  TFR(17) TFR(29) TFR(16) TFR(24)  x0 += ks2; x1 += ks0 + 2u;
  TFR(13) TFR(15) TFR(26) TFR(6)   x0 += ks0; x1 += ks1 + 3u;
  TFR(17) TFR(29) TFR(16) TFR(24)  x0 += ks1; x1 += ks2 + 4u;
  TFR(13) TFR(15) TFR(26) TFR(6)   x0 += ks2; x1 += ks0 + 5u;
#undef TFR
  return x0 ^ x1;
}

// XLA ErfInv32 (Giles): w = -log1p(-x^2), two-branch polynomial.
__device__ __forceinline__ float erfinv_f32(float x) {
  float w = -log1pf(-x * x);
  float p;
  if (w < 5.0f) {
    w = w - 2.5f;
    p = 2.81022636e-08f;
    p = fmaf(p, w, 3.43273939e-07f);
    p = fmaf(p, w, -3.5233877e-06f);
    p = fmaf(p, w, -4.39150654e-06f);
    p = fmaf(p, w, 0.00021858087f);
    p = fmaf(p, w, -0.00125372503f);
    p = fmaf(p, w, -0.00417768164f);
    p = fmaf(p, w, 0.246640727f);
    p = fmaf(p, w, 1.50140941f);
  } else {
    w = sqrtf(w) - 3.0f;
    p = -0.000200214257f;
    p = fmaf(p, w, 0.000100950558f);
    p = fmaf(p, w, 0.00134934322f);
    p = fmaf(p, w, -0.00367342844f);
    p = fmaf(p, w, 0.00573950773f);
    p = fmaf(p, w, -0.0076224613f);
    p = fmaf(p, w, 0.00943887047f);
    p = fmaf(p, w, 1.00167406f);
    p = fmaf(p, w, 2.83297682f);
  }
  return p * x;
}

// jax.random.normal (fp32): uniform in [nextafter(-1,0), 1) via [1,2)
// bitcast trick (scale folds to exactly 2.0f in fp32), then sqrt(2)*erfinv.
__device__ __forceinline__ float jax_normal(uint32_t idx) {
  uint32_t bits = threefry_bits(idx);
  float f = __uint_as_float((bits >> 9) | 0x3F800000u) - 1.0f;  // [0,1)
  const float lo = -0.99999994f;                                 // nextafter(-1,0)
  float u = fmaf(f, 2.0f, lo);
  u = fmaxf(lo, u);
  return 1.41421356f * erfinv_f32(u);
}

// ---------------- persistent RNN kernel: 1 workgroup per batch ----------
// 512 threads: tids 0..499 are MAC threads (r_th = tid%50 owns rows
// 4*r_th..4*r_th+3; k_th = tid/50 owns k-chunk [20*k_th, 20*k_th+20)).
// W_rec tile (80 floats) lives in VGPRs for the whole kernel.
// tids 0..199 additionally are "finish" threads (one per neuron).
__launch_bounds__(512, 1)
__global__ void rnn_persistent(const float* __restrict__ x,
                               const float* __restrict__ h0,
                               const float* __restrict__ Winp,
                               const float* __restrict__ Wrec,
                               const float* __restrict__ brec,
                               float* __restrict__ out) {
  const int b   = blockIdx.x;
  const int tid = threadIdx.x;

  __shared__ float sh_h[NR];          // current hidden state
  __shared__ float sh_part[NR * 11];  // partials, stride 11 (gcd(11,32)=1)
  __shared__ float sh_x[NI];          // x_t staging

  const int  k_th = tid / 50;         // 0..9 for active MAC threads
  const int  r_th = tid % 50;
  const bool mac_active = (tid < 500);

  // --- load stationary W_rec tile into registers (float4, aligned) ---
  float w[4][20];
  if (mac_active) {
#pragma unroll
    for (int j = 0; j < 4; ++j) {
      const float* wr = Wrec + (size_t)(4 * r_th + j) * NR + 20 * k_th;
#pragma unroll
      for (int q = 0; q < 5; ++q) {
        float4 v = *(const float4*)(wr + 4 * q);
        w[j][4 * q + 0] = v.x; w[j][4 * q + 1] = v.y;
        w[j][4 * q + 2] = v.z; w[j][4 * q + 3] = v.w;
      }
    }
  }

  // --- finish-thread state: W_inp row, bias, h in register ---
  float winp[NI];
  float brec_r = 0.0f;
  float h_reg  = 0.0f;
  if (tid < NR) {
#pragma unroll
    for (int i = 0; i < NI; ++i) winp[i] = Winp[tid * NI + i];
    brec_r = brec[tid];
    h_reg  = h0[(size_t)b * NR + tid];
    sh_h[tid] = h_reg;
  }
  __syncthreads();

  const float* xb = x + (size_t)b * TSTEPS * NI;
  float* ob       = out + (size_t)b * TSTEPS * NR;

  for (int t = 0; t < TSTEPS; ++t) {
    // ---------- phase A: MACs from sh_h, plus x-load and noise ----------
    float xv = 0.0f;
    if (tid < NI) xv = xb[t * NI + tid];   // issue global load early

    float eta = 0.0f;
    if (tid < NR) {
      // flat index into eta[T][B][NR]
      uint32_t idx = (uint32_t)t * (uint32_t)(NB * NR)
                   + (uint32_t)b * (uint32_t)NR + (uint32_t)tid;
      eta = NOISE_STD_F * jax_normal(idx);
    }

    if (mac_active) {
      float a0 = 0.0f, a1 = 0.0f, a2 = 0.0f, a3 = 0.0f;
      const float* hp = sh_h + 20 * k_th;  // 16B-aligned (80B stride)
#pragma unroll
      for (int q = 0; q < 5; ++q) {
        float4 hv = *(const float4*)(hp + 4 * q);
        a0 = fmaf(w[0][4 * q + 0], hv.x, a0);
        a1 = fmaf(w[1][4 * q + 0], hv.x, a1);
        a2 = fmaf(w[2][4 * q + 0], hv.x, a2);
        a3 = fmaf(w[3][4 * q + 0], hv.x, a3);
        a0 = fmaf(w[0][4 * q + 1], hv.y, a0);
        a1 = fmaf(w[1][4 * q + 1], hv.y, a1);
        a2 = fmaf(w[2][4 * q + 1], hv.y, a2);
        a3 = fmaf(w[3][4 * q + 1], hv.y, a3);
        a0 = fmaf(w[0][4 * q + 2], hv.z, a0);
        a1 = fmaf(w[1][4 * q + 2], hv.z, a1);
        a2 = fmaf(w[2][4 * q + 2], hv.z, a2);
        a3 = fmaf(w[3][4 * q + 2], hv.z, a3);
        a0 = fmaf(w[0][4 * q + 3], hv.w, a0);
        a1 = fmaf(w[1][4 * q + 3], hv.w, a1);
        a2 = fmaf(w[2][4 * q + 3], hv.w, a2);
        a3 = fmaf(w[3][4 * q + 3], hv.w, a3);
      }
      sh_part[(4 * r_th + 0) * 11 + k_th] = a0;
      sh_part[(4 * r_th + 1) * 11 + k_th] = a1;
      sh_part[(4 * r_th + 2) * 11 + k_th] = a2;
      sh_part[(4 * r_th + 3) * 11 + k_th] = a3;
    }
    if (tid < NI) sh_x[tid] = xv;
    __syncthreads();

    // ---------- phase B: reduce + input drive + tanh + state update -----
    if (tid < NR) {
      float y = brec_r;
#pragma unroll
      for (int q = 0; q < 10; ++q) y += sh_part[tid * 11 + q];
#pragma unroll
      for (int i = 0; i < NI; ++i) y = fmaf(winp[i], sh_x[i], y);
      float rate = tanhf(y);
      float hn = h_reg + ALPHA_F * (((-h_reg) + rate) + eta);
      h_reg = hn;
      sh_h[tid] = hn;
      ob[(size_t)t * NR + tid] = hn;
    }
    __syncthreads();
  }
}

extern "C" void kernel_launch(void* const* d_in, const int* in_sizes, int n_in,
                              void* d_out, int out_size, void* d_ws, size_t ws_size,
                              hipStream_t stream) {
  const float* x    = (const float*)d_in[0];  // [256,1000,10]
  const float* h0   = (const float*)d_in[1];  // [256,200]
  const float* Winp = (const float*)d_in[2];  // [200,10]
  const float* Wrec = (const float*)d_in[3];  // [200,200]
  const float* brec = (const float*)d_in[4];  // [200]
  float* out = (float*)d_out;                 // [256,1000,200]
  (void)in_sizes; (void)n_in; (void)out_size; (void)d_ws; (void)ws_size;

  rnn_persistent<<<dim3(NB), dim3(512), 0, stream>>>(x, h0, Winp, Wrec, brec, out);
}

// Round 2
// 1130.740 us; speedup vs baseline: 1.1333x; 1.1333x over previous
//
#include <hip/hip_runtime.h>
#include <cstdint>
#include <cstddef>

#define TSTEPS 1000
#define NB     256
#define NR     200
#define NI     10
#define ALPHA_F     0.1f
#define NOISE_STD_F 0.01f

// ---------------- JAX threefry2x32-20, key = (0, 42) --------------------
// Partitionable variant: element j uses counter (hi=0, lo=j); draw = x0^x1.
__device__ __forceinline__ uint32_t rotl32(uint32_t v, uint32_t d) {
  return (v << d) | (v >> (32u - d));
}

__device__ __forceinline__ uint32_t threefry_bits(uint32_t c1) {
  const uint32_t ks0 = 0u;
  const uint32_t ks1 = 42u;
  const uint32_t ks2 = 0x1BD11BDAu ^ ks0 ^ ks1;
  uint32_t x0 = ks0;
  uint32_t x1 = c1 + ks1;
#define TFR(r) { x0 += x1; x1 = rotl32(x1, (r)); x1 ^= x0; }
  TFR(13) TFR(15) TFR(26) TFR(6)   x0 += ks1; x1 += ks2 + 1u;
  TFR(17) TFR(29) TFR(16) TFR(24)  x0 += ks2; x1 += ks0 + 2u;
  TFR(13) TFR(15) TFR(26) TFR(6)   x0 += ks0; x1 += ks1 + 3u;
  TFR(17) TFR(29) TFR(16) TFR(24)  x0 += ks1; x1 += ks2 + 4u;
  TFR(13) TFR(15) TFR(26) TFR(6)   x0 += ks2; x1 += ks0 + 5u;
#undef TFR
  return x0 ^ x1;
}

// XLA ErfInv32 (Giles). log1p(-x^2) -> __logf(fma(-x,x,1)): |u|<=1-2^-24
// keeps the argument >= 2^-23, tail error << threshold.
__device__ __forceinline__ float erfinv_f32(float x) {
  float w = -__logf(fmaf(-x, x, 1.0f));
  float p;
  if (w < 5.0f) {
    w = w - 2.5f;
    p = 2.81022636e-08f;
    p = fmaf(p, w, 3.43273939e-07f);
    p = fmaf(p, w, -3.5233877e-06f);
    p = fmaf(p, w, -4.39150654e-06f);
    p = fmaf(p, w, 0.00021858087f);
    p = fmaf(p, w, -0.00125372503f);
    p = fmaf(p, w, -0.00417768164f);
    p = fmaf(p, w, 0.246640727f);
    p = fmaf(p, w, 1.50140941f);
  } else {
    w = sqrtf(w) - 3.0f;
    p = -0.000200214257f;
    p = fmaf(p, w, 0.000100950558f);
    p = fmaf(p, w, 0.00134934322f);
    p = fmaf(p, w, -0.00367342844f);
    p = fmaf(p, w, 0.00573950773f);
    p = fmaf(p, w, -0.0076224613f);
    p = fmaf(p, w, 0.00943887047f);
    p = fmaf(p, w, 1.00167406f);
    p = fmaf(p, w, 2.83297682f);
  }
  return p * x;
}

__device__ __forceinline__ float jax_normal(uint32_t idx) {
  uint32_t bits = threefry_bits(idx);
  float f = __uint_as_float((bits >> 9) | 0x3F800000u) - 1.0f;  // [0,1)
  const float lo = -0.99999994f;                                 // nextafter(-1,0)
  float u = fmaf(f, 2.0f, lo);
  u = fmaxf(lo, u);
  return 1.41421356f * erfinv_f32(u);
}

// exp-based tanh: ~2ulp, no ocml branches. tanh(y)=sign(y)*(1-t)/(1+t),
// t=exp(-2|y|).
__device__ __forceinline__ float tanh_fast(float y) {
  float ay = fabsf(y);
  float t  = __expf(-2.0f * ay);
  float r  = (1.0f - t) * __frcp_rn(1.0f + t);
  return copysignf(r, y);
}

// LDS-only barrier: orders DS ops without draining vmcnt (keeps the per-step
// global `out` stores in flight — __syncthreads would wait vmcnt(0)).
__device__ __forceinline__ void wg_barrier_lds() {
  asm volatile("s_waitcnt lgkmcnt(0)\n\ts_barrier" ::: "memory");
}

// ---------------- persistent RNN kernel: 1 workgroup per batch ----------
// 512 threads = 8 waves.
//  Phase A (all): tid<500 MAC threads: r=tid%50 owns rows 4r..4r+3,
//                 k=tid/50 owns k-chunk [20k,20k+20). Partials -> LDS
//                 k-major (one conflict-free ds_write_b128/thread).
//  Phase B: waves 0-3 (tid<200): reduce + input drive + tanh + update.
//           waves 4-5 (tid 256..367): Threefry noise for step t+1 (dbuf).
//           wave  7  (tid 448..457): global load x(t+1) (dbuf).
__launch_bounds__(512, 2)
__global__ void rnn_persistent(const float* __restrict__ x,
                               const float* __restrict__ h0,
                               const float* __restrict__ Winp,
                               const float* __restrict__ Wrec,
                               const float* __restrict__ brec,
                               float* __restrict__ out) {
  const int b   = blockIdx.x;
  const int tid = threadIdx.x;

  __shared__ float sh_h[NR];            // current hidden state
  __shared__ float sh_part[10 * NR];    // partials, k-major: [k*200 + row]
  __shared__ float sh_x[2][16];         // x_t double buffer
  __shared__ float sh_eta[2][NR];       // scaled noise double buffer

  const int  k_th = tid / 50;
  const int  r_th = tid % 50;
  const bool mac_active = (tid < 500);

  // --- stationary W_rec tile in registers ---
  float w[4][20];
  if (mac_active) {
#pragma unroll
    for (int j = 0; j < 4; ++j) {
      const float* wr = Wrec + (size_t)(4 * r_th + j) * NR + 20 * k_th;
#pragma unroll
      for (int q = 0; q < 5; ++q) {
        float4 v = *(const float4*)(wr + 4 * q);
        w[j][4 * q + 0] = v.x; w[j][4 * q + 1] = v.y;
        w[j][4 * q + 2] = v.z; w[j][4 * q + 3] = v.w;
      }
    }
  }

  // --- update-thread state ---
  float winp[NI];
  float brec_r = 0.0f;
  float h_reg  = 0.0f;
  if (tid < NR) {
#pragma unroll
    for (int i = 0; i < NI; ++i) winp[i] = Winp[tid * NI + i];
    brec_r = brec[tid];
    h_reg  = h0[(size_t)b * NR + tid];
    sh_h[tid] = h_reg;
  }

  const float* xb = x + (size_t)b * TSTEPS * NI;
  float* ob       = out + (size_t)b * TSTEPS * NR;

  // --- bootstrap: eta(0) and x(0) into buffer 0 ---
  if (tid >= 256 && tid < 368) {
    int n = tid - 256;
    uint32_t base = (uint32_t)b * (uint32_t)NR;  // t = 0
    sh_eta[0][n] = NOISE_STD_F * jax_normal(base + (uint32_t)n);
    if (n < 88) {
      int n2 = n + 112;
      sh_eta[0][n2] = NOISE_STD_F * jax_normal(base + (uint32_t)n2);
    }
  }
  if (tid >= 448 && tid < 448 + NI) {
    sh_x[0][tid - 448] = xb[tid - 448];
  }
  __syncthreads();

  for (int t = 0; t < TSTEPS; ++t) {
    const int cur = t & 1;
    const int nxt = cur ^ 1;

    // ---------- phase A: MACs from sh_h ----------
    if (mac_active) {
      float a0 = 0.0f, a1 = 0.0f, a2 = 0.0f, a3 = 0.0f;
      const float* hp = sh_h + 20 * k_th;  // 16B aligned
#pragma unroll
      for (int q = 0; q < 5; ++q) {
        float4 hv = *(const float4*)(hp + 4 * q);
        a0 = fmaf(w[0][4 * q + 0], hv.x, a0);
        a1 = fmaf(w[1][4 * q + 0], hv.x, a1);
        a2 = fmaf(w[2][4 * q + 0], hv.x, a2);
        a3 = fmaf(w[3][4 * q + 0], hv.x, a3);
        a0 = fmaf(w[0][4 * q + 1], hv.y, a0);
        a1 = fmaf(w[1][4 * q + 1], hv.y, a1);
        a2 = fmaf(w[2][4 * q + 1], hv.y, a2);
        a3 = fmaf(w[3][4 * q + 1], hv.y, a3);
        a0 = fmaf(w[0][4 * q + 2], hv.z, a0);
        a1 = fmaf(w[1][4 * q + 2], hv.z, a1);
        a2 = fmaf(w[2][4 * q + 2], hv.z, a2);
        a3 = fmaf(w[3][4 * q + 2], hv.z, a3);
        a0 = fmaf(w[0][4 * q + 3], hv.w, a0);
        a1 = fmaf(w[1][4 * q + 3], hv.w, a1);
        a2 = fmaf(w[2][4 * q + 3], hv.w, a2);
        a3 = fmaf(w[3][4 * q + 3], hv.w, a3);
      }
      // k-major float4 write: conflict-free, 16B aligned (200%4==0)
      float4 pv = make_float4(a0, a1, a2, a3);
      *(float4*)(sh_part + k_th * NR + 4 * r_th) = pv;
    }
    wg_barrier_lds();

    // ---------- phase B ----------
    if (tid < NR) {
      float y = brec_r;
#pragma unroll
      for (int q = 0; q < 10; ++q) y += sh_part[q * NR + tid];
#pragma unroll
      for (int i = 0; i < NI; ++i) y = fmaf(winp[i], sh_x[cur][i], y);
      float rate = tanh_fast(y);
      float eta  = sh_eta[cur][tid];
      float hn = h_reg + ALPHA_F * (((-h_reg) + rate) + eta);
      h_reg = hn;
      sh_h[tid] = hn;
      ob[(size_t)t * NR + tid] = hn;
    } else if (tid >= 256 && tid < 368) {
      if (t + 1 < TSTEPS) {
        int n = tid - 256;
        uint32_t base = (uint32_t)(t + 1) * (uint32_t)(NB * NR)
                      + (uint32_t)b * (uint32_t)NR;
        sh_eta[nxt][n] = NOISE_STD_F * jax_normal(base + (uint32_t)n);
        if (n < 88) {
          int n2 = n + 112;
          sh_eta[nxt][n2] = NOISE_STD_F * jax_normal(base + (uint32_t)n2);
        }
      }
    } else if (tid >= 448 && tid < 448 + NI) {
      if (t + 1 < TSTEPS) {
        sh_x[nxt][tid - 448] = xb[(t + 1) * NI + (tid - 448)];
      }
    }
    wg_barrier_lds();
  }
}

extern "C" void kernel_launch(void* const* d_in, const int* in_sizes, int n_in,
                              void* d_out, int out_size, void* d_ws, size_t ws_size,
                              hipStream_t stream) {
  const float* x    = (const float*)d_in[0];  // [256,1000,10]
  const float* h0   = (const float*)d_in[1];  // [256,200]
  const float* Winp = (const float*)d_in[2];  // [200,10]
  const float* Wrec = (const float*)d_in[3];  // [200,200]
  const float* brec = (const float*)d_in[4];  // [200]
  float* out = (float*)d_out;                 // [256,1000,200]
  (void)in_sizes; (void)n_in; (void)out_size; (void)d_ws; (void)ws_size;

  rnn_persistent<<<dim3(NB), dim3(512), 0, stream>>>(x, h0, Winp, Wrec, brec, out);
}